// Round 2
// baseline (202.506 us; speedup 1.0000x reference)
//
#include <hip/hip_runtime.h>
#include <hip/hip_fp16.h>
#include <math.h>

#define B_SZ 16
#define N_SZ 16384
#define T_FR 128      // frames per block
#define NBIN 65       // spectral bins
#define NMEL 80
#define MROW_H 74     // mags LDS row stride in halves (148 B = 37 words, odd -> conflict-free)
#define WP 5          // wcol2 row stride in half2 (20 B = 5 words, odd)

// cos(k*pi/64) for k = 0..32 (quarter-wave table for 128-pt FFT)
constexpr float QC[33] = {
  1.0f,            0.99879545620f, 0.99518472667f, 0.98917650996f,
  0.98078528040f,  0.97003125319f, 0.95694033573f, 0.94154406518f,
  0.92387953251f,  0.90398929312f, 0.88192126435f, 0.85772861000f,
  0.83146961230f,  0.80320753148f, 0.77301045336f, 0.74095112535f,
  0.70710678119f,  0.67155895485f, 0.63439328416f, 0.59569930449f,
  0.55557023302f,  0.51410274419f, 0.47139673683f, 0.42755509343f,
  0.38268343236f,  0.33688985339f, 0.29028467725f, 0.24298017990f,
  0.19509032202f,  0.14673047446f, 0.09801714033f, 0.04906767433f,
  0.0f
};

__host__ __device__ constexpr float cosi(int k) {   // cos(pi*k/64)
  k = ((k % 128) + 128) % 128;
  return (k <= 32) ? QC[k]
       : (k <= 64) ? -QC[64 - k]
       : (k <= 96) ? -QC[k - 64]
       : QC[128 - k];
}
__host__ __device__ constexpr float sini(int k) { return cosi(k - 32); }  // sin(pi*k/64)
__host__ __device__ constexpr float hannw(int n) { return 0.5f - 0.5f * cosi(n); }
__host__ __device__ constexpr int rev6(int m) {
  return ((m & 1) << 5) | ((m & 2) << 3) | ((m & 4) << 1) |
         ((m & 8) >> 1) | ((m & 16) >> 3) | ((m & 32) >> 5);
}

template <int LEN>
__device__ __forceinline__ void fft_stage(float (&zr)[64], float (&zi)[64]) {
#pragma unroll
  for (int i = 0; i < 64; i += LEN) {
#pragma unroll
    for (int j = 0; j < LEN / 2; ++j) {
      const int   q  = 128 * j / LEN;          // twiddle e^{-2*pi*i*j/LEN}
      const float wr = cosi(q);
      const float wi = -sini(q);
      const int   a = i + j, bb = i + j + LEN / 2;
      const float br = zr[bb], bi = zi[bb];
      const float tr = wr * br - wi * bi;
      const float ti = wr * bi + wi * br;
      zr[bb] = zr[a] - tr;
      zi[bb] = zi[a] - ti;
      zr[a] += tr;
      zi[a] += ti;
    }
  }
}

__global__ __launch_bounds__(T_FR, 3) void melspec_kernel(const float* __restrict__ x,
                                                          float* __restrict__ out) {
  __shared__ float   xs[T_FR + 128];
  __shared__ __half  mags[T_FR * MROW_H];
  __shared__ float   melk[NBIN];
  __shared__ __half2 wcol2[NMEL * WP];
  __shared__ int     kpair[NMEL];

  const int tid = threadIdx.x;
  const int t0  = blockIdx.x * T_FR;
  const int b   = blockIdx.y;
  const float* xrow = x + (size_t)b * N_SZ;

  // ---- load input chunk (zero-pad past row end; pad does NOT wrap rows) ----
  for (int i = tid; i < T_FR + 128; i += T_FR) {
    const int g = t0 + i;
    xs[i] = (g < N_SZ) ? xrow[g] : 0.0f;
  }
  // mel position of each spectral bin (bin k -> k*125 Hz)
  if (tid >= 1 && tid < NBIN) {
    melk[tid] = 1127.0f * log1pf((float)tid * (125.0f / 700.0f));
  }
  __syncthreads();

  // ---- build sparse mel columns: 8 taps starting at even bin kbe ----
  if (tid < NMEL) {
    const float mlo = 1127.0f * log1pf(80.0f / 700.0f);
    const float mhi = 1127.0f * log1pf(7600.0f / 700.0f);
    const float dm  = (mhi - mlo) / 81.0f;     // 82 edges -> 81 gaps
    const float inv = 1.0f / dm;
    const float lower = mlo + dm * (float)tid;
    const float upper = lower + 2.0f * dm;
    int kb = 64;
    for (int k = 1; k < NBIN; ++k) {
      if (fminf(melk[k] - lower, upper - melk[k]) > 0.0f) { kb = k; break; }
    }
    const int kbe = kb & ~1;
#pragma unroll
    for (int r = 0; r < 4; ++r) {
      const int k0 = kbe + 2 * r, k1 = k0 + 1;
      float w0 = 0.0f, w1 = 0.0f;
      if (k0 >= 1 && k0 < NBIN)
        w0 = fmaxf(0.0f, fminf((melk[k0] - lower) * inv, (upper - melk[k0]) * inv));
      if (k1 >= 1 && k1 < NBIN)
        w1 = fmaxf(0.0f, fminf((melk[k1] - lower) * inv, (upper - melk[k1]) * inv));
      wcol2[tid * WP + r] = __floats2half2_rn(w0, w1);
    }
    kpair[tid] = kbe >> 1;
  }

  // ---- per-thread 128-pt real FFT (as 64-pt complex), window folded in ----
  float zr[64], zi[64];
  {
    const float* xf = xs + tid;
#pragma unroll
    for (int m = 0; m < 64; ++m) {
      const int rm = rev6(m);                  // compile-time bit-reversal
      zr[m] = xf[2 * rm]     * hannw(2 * rm);
      zi[m] = xf[2 * rm + 1] * hannw(2 * rm + 1);
    }
  }
  fft_stage<2>(zr, zi);
  fft_stage<4>(zr, zi);
  fft_stage<8>(zr, zi);
  fft_stage<16>(zr, zi);
  fft_stage<32>(zr, zi);
  fft_stage<64>(zr, zi);

  // ---- real split + magnitude -> LDS (packed half2 writes) ----
  {
    __half2* mrow2 = (__half2*)(mags + (size_t)tid * MROW_H);
#pragma unroll
    for (int p = 0; p < MROW_H / 2; ++p) {
      float m0 = 0.0f, m1 = 0.0f;
#pragma unroll
      for (int h = 0; h < 2; ++h) {
        const int k = 2 * p + h;
        if (k < NBIN) {
          const int ka = k & 63, kc = (64 - k) & 63;
          const float Ar = zr[ka], Ai = zi[ka];
          const float Br = zr[kc], Bi = zi[kc];
          const float c = cosi(k), s = sini(k);
          const float Xr = (Ar + Br) + c * (Ai + Bi) - s * (Ar - Br);
          const float Xi = (Ai - Bi) - c * (Ar - Br) - s * (Ai + Bi);
          const float mg = 0.5f * sqrtf(Xr * Xr + Xi * Xi);
          if (h == 0) m0 = mg; else m1 = mg;
        }
      }
      mrow2[p] = __floats2half2_rn(m0, m1);
    }
  }

  __syncthreads();

  // ---- outputs: out[b][t][0] = x, out[b][t][1+j] = sparse matvec (half2 FMA) ----
  float* orow = out + ((size_t)b * N_SZ + t0) * 81;
  for (int idx = tid; idx < T_FR * 81; idx += T_FR) {
    const int t = idx / 81;
    const int c = idx - t * 81;
    float v;
    if (c == 0) {
      v = xs[t];
    } else {
      const int j  = c - 1;
      const int p0 = kpair[j];
      const __half2* mg = (const __half2*)(mags + (size_t)t * MROW_H) + p0;
      const __half2* wv = wcol2 + j * WP;
      __half2 acc = __hmul2(wv[0], mg[0]);
      acc = __hfma2(wv[1], mg[1], acc);
      acc = __hfma2(wv[2], mg[2], acc);
      acc = __hfma2(wv[3], mg[3], acc);
      v = __low2float(acc) + __high2float(acc);
    }
    orow[idx] = v;   // consecutive tid -> consecutive addresses (coalesced)
  }
}

extern "C" void kernel_launch(void* const* d_in, const int* in_sizes, int n_in,
                              void* d_out, int out_size, void* d_ws, size_t ws_size,
                              hipStream_t stream) {
  const float* x = (const float*)d_in[0];
  float* out = (float*)d_out;
  dim3 grid(N_SZ / T_FR, B_SZ);
  dim3 block(T_FR);
  hipLaunchKernelGGL(melspec_kernel, grid, block, 0, stream, x, out);
}

// Round 3
// 180.061 us; speedup vs baseline: 1.1246x; 1.1246x over previous
//
#include <hip/hip_runtime.h>
#include <hip/hip_fp16.h>
#include <math.h>

#define B_SZ 16
#define N_SZ 16384
#define T_FR 128      // frames per block
#define NBIN 65       // spectral bins
#define NMEL 80
#define MROW_H 76     // mags LDS row stride in halves (152 B, 8B-aligned; word stride 38 -> 2-way bank alias = free)
#define WP 6          // wcol2 row stride in half2 (24 B, 8B-aligned; word stride 6 -> 2-way alias = free)

struct __align__(8) h2x2 { __half2 a, b; };

// cos(k*pi/64) for k = 0..32 (quarter-wave table for 128-pt FFT)
constexpr float QC[33] = {
  1.0f,            0.99879545620f, 0.99518472667f, 0.98917650996f,
  0.98078528040f,  0.97003125319f, 0.95694033573f, 0.94154406518f,
  0.92387953251f,  0.90398929312f, 0.88192126435f, 0.85772861000f,
  0.83146961230f,  0.80320753148f, 0.77301045336f, 0.74095112535f,
  0.70710678119f,  0.67155895485f, 0.63439328416f, 0.59569930449f,
  0.55557023302f,  0.51410274419f, 0.47139673683f, 0.42755509343f,
  0.38268343236f,  0.33688985339f, 0.29028467725f, 0.24298017990f,
  0.19509032202f,  0.14673047446f, 0.09801714033f, 0.04906767433f,
  0.0f
};

__host__ __device__ constexpr float cosi(int k) {   // cos(pi*k/64)
  k = ((k % 128) + 128) % 128;
  return (k <= 32) ? QC[k]
       : (k <= 64) ? -QC[64 - k]
       : (k <= 96) ? -QC[k - 64]
       : QC[128 - k];
}
__host__ __device__ constexpr float sini(int k) { return cosi(k - 32); }  // sin(pi*k/64)
__host__ __device__ constexpr float hannw(int n) { return 0.5f - 0.5f * cosi(n); }
__host__ __device__ constexpr int rev6(int m) {
  return ((m & 1) << 5) | ((m & 2) << 3) | ((m & 4) << 1) |
         ((m & 8) >> 1) | ((m & 16) >> 3) | ((m & 32) >> 5);
}

template <int LEN>
__device__ __forceinline__ void fft_stage(float (&zr)[64], float (&zi)[64]) {
#pragma unroll
  for (int i = 0; i < 64; i += LEN) {
#pragma unroll
    for (int j = 0; j < LEN / 2; ++j) {
      const int   q  = 128 * j / LEN;          // twiddle e^{-2*pi*i*j/LEN}
      const float wr = cosi(q);
      const float wi = -sini(q);
      const int   a = i + j, bb = i + j + LEN / 2;
      const float br = zr[bb], bi = zi[bb];
      const float tr = wr * br - wi * bi;
      const float ti = wr * bi + wi * br;
      zr[bb] = zr[a] - tr;
      zi[bb] = zi[a] - ti;
      zr[a] += tr;
      zi[a] += ti;
    }
  }
}

// NOTE: no min-waves arg — forcing 3 waves/EU capped VGPR at 84 and spilled the
// 128-reg FFT arrays to scratch (+375 MB HBM traffic, R2 regression). Floor ~152.
__global__ __launch_bounds__(T_FR) void melspec_kernel(const float* __restrict__ x,
                                                       float* __restrict__ out) {
  __shared__ float   xs[T_FR + 128];
  __shared__ __align__(16) __half mags[T_FR * MROW_H];
  __shared__ float   melk[NBIN];
  __shared__ __align__(8) __half2 wcol2[NMEL * WP];
  __shared__ int     khalf[NMEL];   // (first-support-bin & ~3) >> 1  (even)

  const int tid = threadIdx.x;
  const int t0  = blockIdx.x * T_FR;
  const int b   = blockIdx.y;
  const float* xrow = x + (size_t)b * N_SZ;

  // ---- load input chunk (zero-pad past row end; pad does NOT wrap rows) ----
  for (int i = tid; i < T_FR + 128; i += T_FR) {
    const int g = t0 + i;
    xs[i] = (g < N_SZ) ? xrow[g] : 0.0f;
  }
  // mel position of each spectral bin (bin k -> k*125 Hz)
  if (tid >= 1 && tid < NBIN) {
    melk[tid] = 1127.0f * log1pf((float)tid * (125.0f / 700.0f));
  }
  __syncthreads();

  // ---- build sparse mel columns: 8 taps starting at quad-aligned bin kbe ----
  if (tid < NMEL) {
    const float mlo = 1127.0f * log1pf(80.0f / 700.0f);
    const float mhi = 1127.0f * log1pf(7600.0f / 700.0f);
    const float dm  = (mhi - mlo) / 81.0f;     // 82 edges -> 81 gaps
    const float inv = 1.0f / dm;
    const float lower = mlo + dm * (float)tid;
    const float upper = lower + 2.0f * dm;
    int kb = 64;
    for (int k = 1; k < NBIN; ++k) {
      if (fminf(melk[k] - lower, upper - melk[k]) > 0.0f) { kb = k; break; }
    }
    const int kbe = kb & ~3;                   // support width <=5 bins, window of 8 covers it
#pragma unroll
    for (int r = 0; r < 4; ++r) {
      const int k0 = kbe + 2 * r, k1 = k0 + 1;
      float w0 = 0.0f, w1 = 0.0f;
      if (k0 >= 1 && k0 < NBIN)
        w0 = fmaxf(0.0f, fminf((melk[k0] - lower) * inv, (upper - melk[k0]) * inv));
      if (k1 >= 1 && k1 < NBIN)
        w1 = fmaxf(0.0f, fminf((melk[k1] - lower) * inv, (upper - melk[k1]) * inv));
      wcol2[tid * WP + r] = __floats2half2_rn(w0, w1);
    }
    khalf[tid] = kbe >> 1;                     // even -> 8B-aligned half2 index
  }

  // ---- per-thread 128-pt real FFT (as 64-pt complex), window folded in ----
  float zr[64], zi[64];
  {
    const float* xf = xs + tid;
#pragma unroll
    for (int m = 0; m < 64; ++m) {
      const int rm = rev6(m);                  // compile-time bit-reversal
      zr[m] = xf[2 * rm]     * hannw(2 * rm);
      zi[m] = xf[2 * rm + 1] * hannw(2 * rm + 1);
    }
  }
  fft_stage<2>(zr, zi);
  fft_stage<4>(zr, zi);
  fft_stage<8>(zr, zi);
  fft_stage<16>(zr, zi);
  fft_stage<32>(zr, zi);
  fft_stage<64>(zr, zi);

  // ---- real split + magnitude -> LDS (packed half2 writes) ----
  {
    __half2* mrow2 = (__half2*)(mags + (size_t)tid * MROW_H);
#pragma unroll
    for (int p = 0; p < MROW_H / 2; ++p) {
      float m0 = 0.0f, m1 = 0.0f;
#pragma unroll
      for (int h = 0; h < 2; ++h) {
        const int k = 2 * p + h;
        if (k < NBIN) {
          const int ka = k & 63, kc = (64 - k) & 63;
          const float Ar = zr[ka], Ai = zi[ka];
          const float Br = zr[kc], Bi = zi[kc];
          const float c = cosi(k), s = sini(k);
          const float Xr = (Ar + Br) + c * (Ai + Bi) - s * (Ar - Br);
          const float Xi = (Ai - Bi) - c * (Ar - Br) - s * (Ai + Bi);
          const float mg = 0.5f * sqrtf(Xr * Xr + Xi * Xi);
          if (h == 0) m0 = mg; else m1 = mg;
        }
      }
      mrow2[p] = __floats2half2_rn(m0, m1);
    }
  }

  __syncthreads();

  // ---- outputs: out[b][t][0] = x, out[b][t][1+j] = sparse matvec ----
  // 4x ds_read_b64 + 1x ds_read_b32 per mel element; stores coalesced.
  float* orow = out + ((size_t)b * N_SZ + t0) * 81;
  for (int idx = tid; idx < T_FR * 81; idx += T_FR) {
    const int t = idx / 81;
    const int c = idx - t * 81;
    float v;
    if (c == 0) {
      v = xs[t];
    } else {
      const int j  = c - 1;
      const int p0 = khalf[j];                 // even half2 index
      const h2x2* mgp = (const h2x2*)((const __half2*)(mags + (size_t)t * MROW_H) + p0);
      const h2x2* wvp = (const h2x2*)(wcol2 + j * WP);
      const h2x2 m01 = mgp[0], m23 = mgp[1];
      const h2x2 w01 = wvp[0], w23 = wvp[1];
      __half2 acc = __hmul2(w01.a, m01.a);
      acc = __hfma2(w01.b, m01.b, acc);
      acc = __hfma2(w23.a, m23.a, acc);
      acc = __hfma2(w23.b, m23.b, acc);
      v = __low2float(acc) + __high2float(acc);
    }
    orow[idx] = v;   // consecutive tid -> consecutive addresses (coalesced)
  }
}

extern "C" void kernel_launch(void* const* d_in, const int* in_sizes, int n_in,
                              void* d_out, int out_size, void* d_ws, size_t ws_size,
                              hipStream_t stream) {
  const float* x = (const float*)d_in[0];
  float* out = (float*)d_out;
  dim3 grid(N_SZ / T_FR, B_SZ);
  dim3 block(T_FR);
  hipLaunchKernelGGL(melspec_kernel, grid, block, 0, stream, x, out);
}

// Round 4
// 119.013 us; speedup vs baseline: 1.7015x; 1.5130x over previous
//
#include <hip/hip_runtime.h>
#include <hip/hip_fp16.h>
#include <math.h>

#define B_SZ 16
#define N_SZ 16384
#define T_FR 128      // frames per block (= block size)
#define NBIN 65       // spectral bins
#define NMEL 80
#define ST   83       // stage row stride in halves (odd -> conflict-free)
#define KN   6        // taps per mel filter (true max support = 5 bins)

// ---------------- compile-time math ----------------

// cos(k*pi/64) for k = 0..32 (quarter-wave table for 128-pt FFT)
constexpr float QC[33] = {
  1.0f,            0.99879545620f, 0.99518472667f, 0.98917650996f,
  0.98078528040f,  0.97003125319f, 0.95694033573f, 0.94154406518f,
  0.92387953251f,  0.90398929312f, 0.88192126435f, 0.85772861000f,
  0.83146961230f,  0.80320753148f, 0.77301045336f, 0.74095112535f,
  0.70710678119f,  0.67155895485f, 0.63439328416f, 0.59569930449f,
  0.55557023302f,  0.51410274419f, 0.47139673683f, 0.42755509343f,
  0.38268343236f,  0.33688985339f, 0.29028467725f, 0.24298017990f,
  0.19509032202f,  0.14673047446f, 0.09801714033f, 0.04906767433f,
  0.0f
};

__host__ __device__ constexpr float cosi(int k) {   // cos(pi*k/64)
  k = ((k % 128) + 128) % 128;
  return (k <= 32) ? QC[k]
       : (k <= 64) ? -QC[64 - k]
       : (k <= 96) ? -QC[k - 64]
       : QC[128 - k];
}
__host__ __device__ constexpr float sini(int k) { return cosi(k - 32); }  // sin(pi*k/64)
__host__ __device__ constexpr float hannw(int n) { return 0.5f - 0.5f * cosi(n); }
__host__ __device__ constexpr int rev6(int m) {
  return ((m & 1) << 5) | ((m & 2) << 3) | ((m & 4) << 1) |
         ((m & 8) >> 1) | ((m & 16) >> 3) | ((m & 32) >> 5);
}

// constexpr natural log (double), range-reduced atanh series; ~1e-16 accurate
constexpr double cln(double x) {
  int k = 0;
  while (x > 1.5)  { x *= 0.5; ++k; }
  while (x < 0.75) { x *= 2.0; --k; }
  const double y = (x - 1.0) / (x + 1.0);
  const double y2 = y * y;
  double t = y, s = 0.0;
  for (int i = 0; i < 40; ++i) { s += t / (double)(2 * i + 1); t *= y2; }
  return 2.0 * s + (double)k * 0.69314718055994530942;
}
constexpr double melf(double f) { return 1127.0 * cln(1.0 + f / 700.0); }

// compile-time sparse mel filterbank: per filter j, start bin kbe[j] + KN weights
struct MelTab {
  int   kbe[NMEL];
  float w[NMEL][KN];
  constexpr MelTab() : kbe{}, w{} {
    const double mlo = melf(80.0), mhi = melf(7600.0);
    const double dm  = (mhi - mlo) / 81.0;     // 82 edges -> 81 gaps
    for (int j = 0; j < NMEL; ++j) {
      const double lower = mlo + dm * (double)j;
      const double upper = lower + 2.0 * dm;
      int kb = 64;
      for (int k = 1; k < NBIN; ++k) {
        const double m = melf(125.0 * (double)k);
        const double a = m - lower, b2 = upper - m;
        if ((a < b2 ? a : b2) > 0.0) { kb = k; break; }
      }
      if (kb > NBIN - KN) kb = NBIN - KN;      // keep kb+KN-1 <= 64 (never triggers in practice)
      kbe[j] = kb;
      for (int r = 0; r < KN; ++r) {
        const int k = kb + r;
        double ww = 0.0;
        if (k >= 1 && k < NBIN) {
          const double m = melf(125.0 * (double)k);
          const double a = (m - lower) / dm, b2 = (upper - m) / dm;
          ww = a < b2 ? a : b2;
          if (ww < 0.0) ww = 0.0;
        }
        w[j][r] = (float)ww;
      }
    }
  }
};
constexpr MelTab MT{};

// ---------------- FFT ----------------

template <int LEN>
__device__ __forceinline__ void fft_stage(float (&zr)[64], float (&zi)[64]) {
#pragma unroll
  for (int i = 0; i < 64; i += LEN) {
#pragma unroll
    for (int j = 0; j < LEN / 2; ++j) {
      const int   q  = 128 * j / LEN;          // twiddle e^{-2*pi*i*j/LEN}
      const float wr = cosi(q);
      const float wi = -sini(q);
      const int   a = i + j, bb = i + j + LEN / 2;
      const float br = zr[bb], bi = zi[bb];
      const float tr = wr * br - wi * bi;
      const float ti = wr * bi + wi * br;
      zr[bb] = zr[a] - tr;
      zi[bb] = zi[a] - ti;
      zr[a] += tr;
      zi[a] += ti;
    }
  }
}

// NOTE: no min-waves launch bound — forcing 3/EU capped VGPR at 84 and spilled
// the 128-reg FFT arrays to scratch (+375 MB HBM, R2 regression). Floor ~140.
__global__ __launch_bounds__(T_FR) void melspec_kernel(const float* __restrict__ x,
                                                       float* __restrict__ out) {
  __shared__ float  xs[T_FR + 128];
  __shared__ __half stage[T_FR * ST];          // [t][c] fp16 staging, stride 83

  const int tid = threadIdx.x;
  const int t0  = blockIdx.x * T_FR;
  const int b   = blockIdx.y;
  const float* xrow = x + (size_t)b * N_SZ;

  // ---- load input chunk (zero-pad past row end; pad does NOT wrap rows) ----
  for (int i = tid; i < T_FR + 128; i += T_FR) {
    const int g = t0 + i;
    xs[i] = (g < N_SZ) ? xrow[g] : 0.0f;
  }
  __syncthreads();

  // ---- per-thread 128-pt real FFT (as 64-pt complex), window folded in ----
  float zr[64], zi[64];
  {
    const float* xf = xs + tid;
#pragma unroll
    for (int m = 0; m < 64; ++m) {
      const int rm = rev6(m);                  // compile-time bit-reversal
      zr[m] = xf[2 * rm]     * hannw(2 * rm);
      zi[m] = xf[2 * rm + 1] * hannw(2 * rm + 1);
    }
  }
  fft_stage<2>(zr, zi);
  fft_stage<4>(zr, zi);
  fft_stage<8>(zr, zi);
  fft_stage<16>(zr, zi);
  fft_stage<32>(zr, zi);
  fft_stage<64>(zr, zi);

  // ---- real split + magnitude, kept in registers ----
  float mag[NBIN];
#pragma unroll
  for (int k = 0; k < NBIN; ++k) {
    const int ka = k & 63, kc = (64 - k) & 63;
    const float Ar = zr[ka], Ai = zi[ka];
    const float Br = zr[kc], Bi = zi[kc];
    const float c = cosi(k), s = sini(k);
    const float Xr = (Ar + Br) + c * (Ai + Bi) - s * (Ar - Br);
    const float Xi = (Ai - Bi) - c * (Ar - Br) - s * (Ai + Bi);
    mag[k] = 0.5f * sqrtf(Xr * Xr + Xi * Xi);
  }

  // ---- mel matvec: compile-time sparse taps, register mags -> fp16 stage ----
  {
    __half* srow = stage + tid * ST;
    srow[0] = __float2half(xs[tid]);           // out[...,0] = x
#pragma unroll
    for (int j = 0; j < NMEL; ++j) {
      const int kb = MT.kbe[j];                // compile-time after unroll
      float acc = MT.w[j][0] * mag[kb];
#pragma unroll
      for (int r = 1; r < KN; ++r)
        acc = fmaf(MT.w[j][r], mag[kb + r], acc);  // zero-weight taps fold away
      srow[1 + j] = __float2half(acc);
    }
  }

  __syncthreads();

  // ---- coalesced output: idx = i*128 + tid = t*81 + c, incremental (t,c) ----
  float* orow = out + ((size_t)b * N_SZ + t0) * 81;
  int t = (tid >= 81) ? 1 : 0;
  int c = (tid >= 81) ? tid - 81 : tid;
  for (int i = 0; i < 81; ++i) {
    orow[i * T_FR + tid] = __half2float(stage[t * ST + c]);
    t += 1;
    c += 47;                                   // 128 - 81
    if (c >= 81) { c -= 81; ++t; }
  }
}

extern "C" void kernel_launch(void* const* d_in, const int* in_sizes, int n_in,
                              void* d_out, int out_size, void* d_ws, size_t ws_size,
                              hipStream_t stream) {
  const float* x = (const float*)d_in[0];
  float* out = (float*)d_out;
  dim3 grid(N_SZ / T_FR, B_SZ);
  dim3 block(T_FR);
  hipLaunchKernelGGL(melspec_kernel, grid, block, 0, stream, x, out);
}